// Round 1
// baseline (30545.493 us; speedup 1.0000x reference)
//
#include <hip/hip_runtime.h>
#include <hip/hip_bf16.h>

// Output layout (floats): Objects[8*20*4] @0 | Object_features[8*20*4096] @640
//                        | valid[8*20] @656000 | fullframe_features[8*4096] @656160
#define OBJ_OFF   0
#define FEAT_OFF  640
#define VALID_OFF 656000
#define FF_OFF    656160

// ---------------------------------------------------------------------------
// Kernel 1: per-batch masked top-20 selection (matches lax.top_k ordering)
// ---------------------------------------------------------------------------
__global__ __launch_bounds__(512) void topk_kernel(
    const float* __restrict__ boxes, const float* __restrict__ scores,
    const int* __restrict__ labels, float* __restrict__ d_out,
    float* __restrict__ selbox, float* __restrict__ flags)
{
    __shared__ unsigned long long keys[512];
    __shared__ unsigned long long red[512];
    const int b = blockIdx.x, t = threadIdx.x;

    unsigned long long key = 0ULL;
    if (t < 300) {
        float s = scores[b * 300 + t];
        int   l = labels[b * 300 + t];
        bool cls = (l == 2) || (l == 3) || (l == 4) || (l == 6) || (l == 8);
        if (cls && s > 0.8f) {
            key = ((unsigned long long)__float_as_uint(s) << 32) |
                  (unsigned long long)(unsigned int)(~(unsigned int)t);
        }
    }
    keys[t] = key;
    __syncthreads();

    for (int k = 0; k < 20; ++k) {
        red[t] = keys[t];
        __syncthreads();
        for (int s = 256; s > 0; s >>= 1) {
            if (t < s) red[t] = (red[t] > red[t + s]) ? red[t] : red[t + s];
            __syncthreads();
        }
        unsigned long long m = red[0];
        const int slot = b * 20 + k;
        if (m == 0ULL) {
            if (t == 0) {
                d_out[OBJ_OFF + slot * 4 + 0] = 0.f;
                d_out[OBJ_OFF + slot * 4 + 1] = 0.f;
                d_out[OBJ_OFF + slot * 4 + 2] = 0.f;
                d_out[OBJ_OFF + slot * 4 + 3] = 0.f;
                d_out[VALID_OFF + slot] = 0.f;
                selbox[slot * 4 + 0] = 0.f; selbox[slot * 4 + 1] = 0.f;
                selbox[slot * 4 + 2] = 0.f; selbox[slot * 4 + 3] = 0.f;
                flags[slot] = 0.f;
            }
        } else if (keys[t] == m) {  // unique winner (index embedded in key)
            const float bx0 = boxes[(b * 300 + t) * 4 + 0];
            const float by0 = boxes[(b * 300 + t) * 4 + 1];
            const float bx1 = boxes[(b * 300 + t) * 4 + 2];
            const float by1 = boxes[(b * 300 + t) * 4 + 3];
            d_out[OBJ_OFF + slot * 4 + 0] = bx0;
            d_out[OBJ_OFF + slot * 4 + 1] = by0;
            d_out[OBJ_OFF + slot * 4 + 2] = bx1;
            d_out[OBJ_OFF + slot * 4 + 3] = by1;
            d_out[VALID_OFF + slot] = 1.f;
            selbox[slot * 4 + 0] = bx0; selbox[slot * 4 + 1] = by0;
            selbox[slot * 4 + 2] = bx1; selbox[slot * 4 + 3] = by1;
            bool deg = (bx1 <= bx0) || (by1 <= by0);
            flags[slot] = deg ? 0.f : 1.f;
            keys[t] = 0ULL;
        }
        __syncthreads();
    }
}

// ---------------------------------------------------------------------------
// Conv helper constants
// ---------------------------------------------------------------------------
__device__ __forceinline__ void conv_tile_compute(
    const float (*tile)[67][67], const float (*wl)[16],
    const float* __restrict__ bc, int ocb, int ty, int tx, float* acc)
{
#pragma unroll
    for (int j = 0; j < 16; ++j) acc[j] = 0.f;
#pragma unroll
    for (int c = 0; c < 3; ++c) {
#pragma unroll
        for (int kh = 0; kh < 7; ++kh) {
            const float* trow = &tile[c][ty * 4 + kh][tx * 4];
#pragma unroll
            for (int kw = 0; kw < 7; ++kw) {
                float v = trow[kw];
                const float* wr = wl[c * 49 + kh * 7 + kw];
#pragma unroll
                for (int j = 0; j < 16; ++j) acc[j] += v * wr[j];
            }
        }
    }
}

// ---------------------------------------------------------------------------
// Kernel 2: fullframe conv(7x7 s4 SAME, 3->256) + ReLU + global-avg-pool sum
// grid: (64 tiles, 8 batch), 256 threads. Output: pooled[b][oc] += sums
// ---------------------------------------------------------------------------
__global__ __launch_bounds__(256) void ffconv_kernel(
    const float* __restrict__ x, const float* __restrict__ Wc,
    const float* __restrict__ bc, float* __restrict__ pooled)
{
    __shared__ float tile[3][67][67];
    __shared__ float wl[147][16];

    const int b = blockIdx.y;
    const int tileid = blockIdx.x;                // 8x8 tiles of 16x16 outputs
    const int oy0 = (tileid >> 3) * 16, ox0 = (tileid & 7) * 16;
    const int iy0 = oy0 * 4 - 1, ix0 = ox0 * 4 - 1;   // SAME pad_lo = 1
    const int tid = threadIdx.x;

    const float mean[3] = {0.485f, 0.456f, 0.406f};
    const float istd[3] = {1.0f / 0.229f, 1.0f / 0.224f, 1.0f / 0.225f};

    for (int i = tid; i < 3 * 67 * 67; i += 256) {
        int c = i / (67 * 67), rem = i % (67 * 67);
        int r = rem / 67, col = rem % 67;
        int gy = iy0 + r, gx = ix0 + col;
        float v = 0.f;
        if (gy >= 0 && gy < 512 && gx >= 0 && gx < 512)
            v = (x[((b * 3 + c) * 512 + gy) * 512 + gx] - mean[c]) * istd[c];
        tile[c][r][col] = v;
    }
    const int ty = tid >> 4, tx = tid & 15;
    __syncthreads();

    for (int ocb = 0; ocb < 256; ocb += 16) {
        for (int i = tid; i < 147 * 16; i += 256) {
            int kidx = i >> 4, j = i & 15;
            wl[kidx][j] = Wc[(ocb + j) * 147 + kidx];
        }
        __syncthreads();

        float acc[16];
        conv_tile_compute(tile, wl, bc, ocb, ty, tx, acc);

#pragma unroll
        for (int j = 0; j < 16; ++j) {
            float p = acc[j] + bc[ocb + j];
            p = p > 0.f ? p : 0.f;
            for (int off = 32; off; off >>= 1) p += __shfl_down(p, off);
            if ((tid & 63) == 0) atomicAdd(&pooled[b * 256 + ocb + j], p);
        }
        __syncthreads();
    }
}

// ---------------------------------------------------------------------------
// Kernel 3: RoIAlign 64x64 crop (on-the-fly bilinear + normalize) -> conv
// grid: 160 blocks (b*20+k), 256 threads. Skips invalid/degenerate slots.
// ---------------------------------------------------------------------------
__global__ __launch_bounds__(256) void cropconv_kernel(
    const float* __restrict__ x, const float* __restrict__ Wc,
    const float* __restrict__ bc, const float* __restrict__ selbox,
    const float* __restrict__ flags, float* __restrict__ pooled)
{
    const int bk = blockIdx.x;
    if (flags[bk] == 0.f) return;   // features will be zeroed anyway
    const int b = bk / 20;
    const int tid = threadIdx.x;

    __shared__ float tile[3][67][67];
    __shared__ float wl[147][16];

    const float bx0 = selbox[bk * 4 + 0], by0 = selbox[bk * 4 + 1];
    const float bx1 = selbox[bk * 4 + 2], by1 = selbox[bk * 4 + 3];

    for (int i = tid; i < 3 * 67 * 67; i += 256) ((float*)tile)[i] = 0.f;
    __syncthreads();

    const float mean[3] = {0.485f, 0.456f, 0.406f};
    const float istd[3] = {1.0f / 0.229f, 1.0f / 0.224f, 1.0f / 0.225f};

    for (int i = tid; i < 3 * 64 * 64; i += 256) {
        int c = i >> 12, rem = i & 4095;
        int cy = rem >> 6, cx = rem & 63;
        float tf_y = (cy + 0.5f) * (1.f / 64.f);
        float tf_x = (cx + 0.5f) * (1.f / 64.f);
        float ys = by0 + tf_y * (by1 - by0);
        float xs = bx0 + tf_x * (bx1 - bx0);
        float yf = floorf(ys), xf = floorf(xs);
        float wy = ys - yf, wx = xs - xf;
        int iy0 = min(max((int)yf, 0), 511); int iy1 = min(iy0 + 1, 511);
        int ix0 = min(max((int)xf, 0), 511); int ix1 = min(ix0 + 1, 511);
        const float* img = x + (size_t)(b * 3 + c) * 512 * 512;
        float Ia = img[iy0 * 512 + ix0], Ib = img[iy0 * 512 + ix1];
        float Ic = img[iy1 * 512 + ix0], Id = img[iy1 * 512 + ix1];
        float v = Ia * (1.f - wy) * (1.f - wx) + Ib * (1.f - wy) * wx +
                  Ic * wy * (1.f - wx) + Id * wy * wx;
        v = (v - mean[c]) * istd[c];
        tile[c][cy + 1][cx + 1] = v;   // pad ring stays zero
    }
    const int ty = tid >> 4, tx = tid & 15;
    __syncthreads();

    for (int ocb = 0; ocb < 256; ocb += 16) {
        for (int i = tid; i < 147 * 16; i += 256) {
            int kidx = i >> 4, j = i & 15;
            wl[kidx][j] = Wc[(ocb + j) * 147 + kidx];
        }
        __syncthreads();

        float acc[16];
        conv_tile_compute(tile, wl, bc, ocb, ty, tx, acc);

#pragma unroll
        for (int j = 0; j < 16; ++j) {
            float p = acc[j] + bc[ocb + j];
            p = p > 0.f ? p : 0.f;
            for (int off = 32; off; off >>= 1) p += __shfl_down(p, off);
            if ((tid & 63) == 0) atomicAdd(&pooled[(8 + bk) * 256 + ocb + j], p);
        }
        __syncthreads();
    }
}

// ---------------------------------------------------------------------------
// Kernel 4: FC [168,256] @ Wf[256,4096] + bf, scatter to outputs
// grid: (16 col-blocks, 7 row-groups of 24), 256 threads
// ---------------------------------------------------------------------------
__global__ __launch_bounds__(256) void fc_kernel(
    const float* __restrict__ pooled, const float* __restrict__ Wf,
    const float* __restrict__ bf, const float* __restrict__ flags,
    float* __restrict__ d_out)
{
    __shared__ float p[24][256];
    const int cb = blockIdx.x, rg = blockIdx.y;
    const int tid = threadIdx.x;

    for (int i = tid; i < 24 * 256; i += 256) {
        int r = i >> 8, k = i & 255;
        int R = rg * 24 + r;
        float s = (R < 8) ? (1.f / 16384.f) : (1.f / 256.f);
        p[r][k] = pooled[R * 256 + k] * s;
    }
    __syncthreads();

    float acc[24];
#pragma unroll
    for (int r = 0; r < 24; ++r) acc[r] = 0.f;

    const int col = cb * 256 + tid;
    for (int k = 0; k < 256; k += 4) {
        float w0 = Wf[(k + 0) * 4096 + col];
        float w1 = Wf[(k + 1) * 4096 + col];
        float w2 = Wf[(k + 2) * 4096 + col];
        float w3 = Wf[(k + 3) * 4096 + col];
#pragma unroll
        for (int r = 0; r < 24; ++r) {
            float4 pv = *(const float4*)&p[r][k];
            acc[r] += pv.x * w0 + pv.y * w1 + pv.z * w2 + pv.w * w3;
        }
    }

    const float bias = bf[col];
#pragma unroll
    for (int r = 0; r < 24; ++r) {
        int R = rg * 24 + r;
        float v = acc[r] + bias;
        if (R < 8) {
            d_out[FF_OFF + R * 4096 + col] = v;
        } else {
            int rr = R - 8;
            if (flags[rr] == 0.f) v = 0.f;
            d_out[FEAT_OFF + rr * 4096 + col] = v;
        }
    }
}

// ---------------------------------------------------------------------------
extern "C" void kernel_launch(void* const* d_in, const int* in_sizes, int n_in,
                              void* d_out, int out_size, void* d_ws, size_t ws_size,
                              hipStream_t stream)
{
    const float* x      = (const float*)d_in[0];
    const float* boxes  = (const float*)d_in[1];
    const float* scores = (const float*)d_in[2];
    const int*   labels = (const int*)d_in[3];
    const float* Wc     = (const float*)d_in[4];
    const float* bc     = (const float*)d_in[5];
    const float* Wf     = (const float*)d_in[6];
    const float* bf     = (const float*)d_in[7];
    float* out = (float*)d_out;

    float* pooled = (float*)d_ws;            // [168][256] sums
    float* selbox = pooled + 168 * 256;      // [160][4]
    float* flags  = selbox + 160 * 4;        // [160]

    hipMemsetAsync(d_ws, 0, 168 * 256 * sizeof(float), stream);

    topk_kernel<<<8, 512, 0, stream>>>(boxes, scores, labels, out, selbox, flags);
    ffconv_kernel<<<dim3(64, 8), 256, 0, stream>>>(x, Wc, bc, pooled);
    cropconv_kernel<<<160, 256, 0, stream>>>(x, Wc, bc, selbox, flags, pooled);
    fc_kernel<<<dim3(16, 7), 256, 0, stream>>>(pooled, Wf, bf, flags, out);
}

// Round 2
// 4499.254 us; speedup vs baseline: 6.7890x; 6.7890x over previous
//
#include <hip/hip_runtime.h>
#include <hip/hip_bf16.h>

// Output layout (floats): Objects[8*20*4] @0 | Object_features[8*20*4096] @640
//                        | valid[8*20] @656000 | fullframe_features[8*4096] @656160
#define OBJ_OFF   0
#define FEAT_OFF  640
#define VALID_OFF 656000
#define FF_OFF    656160

// ws layout (floats): pooled[168*256] | selbox[160*4] | flags[160] | Wt[16*147*16]
#define POOLED_N  (168 * 256)
#define SELBOX_N  (160 * 4)
#define FLAGS_N   (160)

// ---------------------------------------------------------------------------
// Kernel 0: transpose conv weights to [g=oc/16][kidx=c*49+kh*7+kw][j=oc%16]
// so the inner loop reads wave-uniform contiguous 16-float rows (-> s_load).
// ---------------------------------------------------------------------------
__global__ __launch_bounds__(256) void prep_kernel(
    const float* __restrict__ Wc, float* __restrict__ Wt)
{
    int i = blockIdx.x * 256 + threadIdx.x;
    if (i >= 16 * 147 * 16) return;
    int g = i / 2352, rem = i % 2352;
    int kidx = rem / 16, j = rem % 16;
    Wt[i] = Wc[(g * 16 + j) * 147 + kidx];
}

// ---------------------------------------------------------------------------
// Kernel 1: per-batch masked top-20 selection (matches lax.top_k ordering)
// ---------------------------------------------------------------------------
__global__ __launch_bounds__(512) void topk_kernel(
    const float* __restrict__ boxes, const float* __restrict__ scores,
    const int* __restrict__ labels, float* __restrict__ d_out,
    float* __restrict__ selbox, float* __restrict__ flags)
{
    __shared__ unsigned long long keys[512];
    __shared__ unsigned long long red[512];
    const int b = blockIdx.x, t = threadIdx.x;

    unsigned long long key = 0ULL;
    if (t < 300) {
        float s = scores[b * 300 + t];
        int   l = labels[b * 300 + t];
        bool cls = (l == 2) || (l == 3) || (l == 4) || (l == 6) || (l == 8);
        if (cls && s > 0.8f) {
            key = ((unsigned long long)__float_as_uint(s) << 32) |
                  (unsigned long long)(unsigned int)(~(unsigned int)t);
        }
    }
    keys[t] = key;
    __syncthreads();

    for (int k = 0; k < 20; ++k) {
        red[t] = keys[t];
        __syncthreads();
        for (int s = 256; s > 0; s >>= 1) {
            if (t < s) red[t] = (red[t] > red[t + s]) ? red[t] : red[t + s];
            __syncthreads();
        }
        unsigned long long m = red[0];
        const int slot = b * 20 + k;
        if (m == 0ULL) {
            if (t == 0) {
                d_out[OBJ_OFF + slot * 4 + 0] = 0.f;
                d_out[OBJ_OFF + slot * 4 + 1] = 0.f;
                d_out[OBJ_OFF + slot * 4 + 2] = 0.f;
                d_out[OBJ_OFF + slot * 4 + 3] = 0.f;
                d_out[VALID_OFF + slot] = 0.f;
                selbox[slot * 4 + 0] = 0.f; selbox[slot * 4 + 1] = 0.f;
                selbox[slot * 4 + 2] = 0.f; selbox[slot * 4 + 3] = 0.f;
                flags[slot] = 0.f;
            }
        } else if (keys[t] == m) {  // unique winner (index embedded in key)
            const float bx0 = boxes[(b * 300 + t) * 4 + 0];
            const float by0 = boxes[(b * 300 + t) * 4 + 1];
            const float bx1 = boxes[(b * 300 + t) * 4 + 2];
            const float by1 = boxes[(b * 300 + t) * 4 + 3];
            d_out[OBJ_OFF + slot * 4 + 0] = bx0;
            d_out[OBJ_OFF + slot * 4 + 1] = by0;
            d_out[OBJ_OFF + slot * 4 + 2] = bx1;
            d_out[OBJ_OFF + slot * 4 + 3] = by1;
            d_out[VALID_OFF + slot] = 1.f;
            selbox[slot * 4 + 0] = bx0; selbox[slot * 4 + 1] = by0;
            selbox[slot * 4 + 2] = bx1; selbox[slot * 4 + 3] = by1;
            bool deg = (bx1 <= bx0) || (by1 <= by0);
            flags[slot] = deg ? 0.f : 1.f;
            keys[t] = 0ULL;
        }
        __syncthreads();
    }
}

// ---------------------------------------------------------------------------
// Shared conv core: tile[3][67][68] in LDS, weights streamed from Wt
// (wave-uniform addresses -> scalar loads). Each thread: 1 pixel, 16 ch.
// ---------------------------------------------------------------------------
#define CONV_CORE(tile, Wt, bc, pooled, pooled_row)                            \
    {                                                                          \
        const int ty = tid >> 4, tx = tid & 15;                                \
        for (int g = 0; g < 16; ++g) {                                         \
            float acc[16];                                                     \
            _Pragma("unroll")                                                  \
            for (int j = 0; j < 16; ++j) acc[j] = 0.f;                         \
            const float* __restrict__ wb = Wt + g * 2352;                      \
            _Pragma("unroll")                                                  \
            for (int c = 0; c < 3; ++c) {                                      \
                _Pragma("unroll")                                              \
                for (int kh = 0; kh < 7; ++kh) {                               \
                    const float* trow = &tile[c][ty * 4 + kh][tx * 4];         \
                    float4 t0 = *(const float4*)(trow);                        \
                    float4 t1 = *(const float4*)(trow + 4);                    \
                    float v[7] = {t0.x, t0.y, t0.z, t0.w, t1.x, t1.y, t1.z};   \
                    const float* __restrict__ wr = wb + (c * 49 + kh * 7) * 16;\
                    _Pragma("unroll")                                          \
                    for (int kw = 0; kw < 7; ++kw) {                           \
                        _Pragma("unroll")                                      \
                        for (int j = 0; j < 16; ++j)                           \
                            acc[j] += v[kw] * wr[kw * 16 + j];                 \
                    }                                                          \
                }                                                              \
            }                                                                  \
            _Pragma("unroll")                                                  \
            for (int j = 0; j < 16; ++j) {                                     \
                float p = acc[j] + bc[g * 16 + j];                             \
                p = p > 0.f ? p : 0.f;                                         \
                for (int off = 32; off; off >>= 1) p += __shfl_down(p, off);   \
                if ((tid & 63) == 0)                                           \
                    atomicAdd(&pooled[(pooled_row) * 256 + g * 16 + j], p);    \
            }                                                                  \
        }                                                                      \
    }

// ---------------------------------------------------------------------------
// Kernel 2: fullframe conv(7x7 s4 SAME, 3->256) + ReLU + avg-pool sums
// grid: (64 tiles, 8 batch) x 256 threads
// ---------------------------------------------------------------------------
__global__ __launch_bounds__(256) void ffconv_kernel(
    const float* __restrict__ x, const float* __restrict__ Wt,
    const float* __restrict__ bc, float* __restrict__ pooled)
{
    __shared__ __align__(16) float tile[3][67][68];

    const int b = blockIdx.y;
    const int tileid = blockIdx.x;                // 8x8 tiles of 16x16 outputs
    const int oy0 = (tileid >> 3) * 16, ox0 = (tileid & 7) * 16;
    const int iy0 = oy0 * 4 - 1, ix0 = ox0 * 4 - 1;   // SAME pad_lo = 1
    const int tid = threadIdx.x;

    const float mean[3] = {0.485f, 0.456f, 0.406f};
    const float istd[3] = {1.0f / 0.229f, 1.0f / 0.224f, 1.0f / 0.225f};

    for (int i = tid; i < 3 * 67 * 68; i += 256) {
        int c = i / (67 * 68), rem = i % (67 * 68);
        int r = rem / 68, col = rem % 68;
        int gy = iy0 + r, gx = ix0 + col;
        float v = 0.f;
        if (col < 67 && gy >= 0 && gy < 512 && gx >= 0 && gx < 512)
            v = (x[((b * 3 + c) * 512 + gy) * 512 + gx] - mean[c]) * istd[c];
        tile[c][r][col] = v;
    }
    __syncthreads();

    CONV_CORE(tile, Wt, bc, pooled, b)
}

// ---------------------------------------------------------------------------
// Kernel 3: RoIAlign 64x64 crop (bilinear + normalize on the fly) -> conv
// grid: 160 blocks (b*20+k) x 256 threads. Skips invalid/degenerate slots.
// ---------------------------------------------------------------------------
__global__ __launch_bounds__(256) void cropconv_kernel(
    const float* __restrict__ x, const float* __restrict__ Wt,
    const float* __restrict__ bc, const float* __restrict__ selbox,
    const float* __restrict__ flags, float* __restrict__ pooled)
{
    const int bk = blockIdx.x;
    if (flags[bk] == 0.f) return;   // features get zeroed anyway
    const int b = bk / 20;
    const int tid = threadIdx.x;

    __shared__ __align__(16) float tile[3][67][68];

    const float bx0 = selbox[bk * 4 + 0], by0 = selbox[bk * 4 + 1];
    const float bx1 = selbox[bk * 4 + 2], by1 = selbox[bk * 4 + 3];

    for (int i = tid; i < 3 * 67 * 68; i += 256) ((float*)tile)[i] = 0.f;
    __syncthreads();

    const float mean[3] = {0.485f, 0.456f, 0.406f};
    const float istd[3] = {1.0f / 0.229f, 1.0f / 0.224f, 1.0f / 0.225f};

    for (int i = tid; i < 3 * 64 * 64; i += 256) {
        int c = i >> 12, rem = i & 4095;
        int cy = rem >> 6, cx = rem & 63;
        float tf_y = (cy + 0.5f) * (1.f / 64.f);
        float tf_x = (cx + 0.5f) * (1.f / 64.f);
        float ys = by0 + tf_y * (by1 - by0);
        float xs = bx0 + tf_x * (bx1 - bx0);
        float yf = floorf(ys), xf = floorf(xs);
        float wy = ys - yf, wx = xs - xf;
        int iy0 = min(max((int)yf, 0), 511); int iy1 = min(iy0 + 1, 511);
        int ix0 = min(max((int)xf, 0), 511); int ix1 = min(ix0 + 1, 511);
        const float* img = x + (size_t)(b * 3 + c) * 512 * 512;
        float Ia = img[iy0 * 512 + ix0], Ib = img[iy0 * 512 + ix1];
        float Ic = img[iy1 * 512 + ix0], Id = img[iy1 * 512 + ix1];
        float v = Ia * (1.f - wy) * (1.f - wx) + Ib * (1.f - wy) * wx +
                  Ic * wy * (1.f - wx) + Id * wy * wx;
        v = (v - mean[c]) * istd[c];
        tile[c][cy + 1][cx + 1] = v;   // pad ring stays zero
    }
    __syncthreads();

    CONV_CORE(tile, Wt, bc, pooled, 8 + bk)
}

// ---------------------------------------------------------------------------
// Kernel 4: FC [168,256] @ Wf[256,4096] + bf, scatter to outputs
// grid: (16 col-blocks, 7 row-groups of 24) x 256 threads
// ---------------------------------------------------------------------------
__global__ __launch_bounds__(256) void fc_kernel(
    const float* __restrict__ pooled, const float* __restrict__ Wf,
    const float* __restrict__ bf, const float* __restrict__ flags,
    float* __restrict__ d_out)
{
    __shared__ float p[24][256];
    const int cb = blockIdx.x, rg = blockIdx.y;
    const int tid = threadIdx.x;

    for (int i = tid; i < 24 * 256; i += 256) {
        int r = i >> 8, k = i & 255;
        int R = rg * 24 + r;
        float s = (R < 8) ? (1.f / 16384.f) : (1.f / 256.f);
        p[r][k] = pooled[R * 256 + k] * s;
    }
    __syncthreads();

    float acc[24];
#pragma unroll
    for (int r = 0; r < 24; ++r) acc[r] = 0.f;

    const int col = cb * 256 + tid;
    for (int k = 0; k < 256; k += 4) {
        float w0 = Wf[(k + 0) * 4096 + col];
        float w1 = Wf[(k + 1) * 4096 + col];
        float w2 = Wf[(k + 2) * 4096 + col];
        float w3 = Wf[(k + 3) * 4096 + col];
#pragma unroll
        for (int r = 0; r < 24; ++r) {
            float4 pv = *(const float4*)&p[r][k];
            acc[r] += pv.x * w0 + pv.y * w1 + pv.z * w2 + pv.w * w3;
        }
    }

    const float bias = bf[col];
#pragma unroll
    for (int r = 0; r < 24; ++r) {
        int R = rg * 24 + r;
        float v = acc[r] + bias;
        if (R < 8) {
            d_out[FF_OFF + R * 4096 + col] = v;
        } else {
            int rr = R - 8;
            if (flags[rr] == 0.f) v = 0.f;
            d_out[FEAT_OFF + rr * 4096 + col] = v;
        }
    }
}

// ---------------------------------------------------------------------------
extern "C" void kernel_launch(void* const* d_in, const int* in_sizes, int n_in,
                              void* d_out, int out_size, void* d_ws, size_t ws_size,
                              hipStream_t stream)
{
    const float* x      = (const float*)d_in[0];
    const float* boxes  = (const float*)d_in[1];
    const float* scores = (const float*)d_in[2];
    const int*   labels = (const int*)d_in[3];
    const float* Wc     = (const float*)d_in[4];
    const float* bc     = (const float*)d_in[5];
    const float* Wf     = (const float*)d_in[6];
    const float* bf     = (const float*)d_in[7];
    float* out = (float*)d_out;

    float* pooled = (float*)d_ws;                 // [168][256] sums
    float* selbox = pooled + POOLED_N;            // [160][4]
    float* flags  = selbox + SELBOX_N;            // [160]
    float* Wt     = flags + FLAGS_N;              // [16][147][16]

    hipMemsetAsync(d_ws, 0, POOLED_N * sizeof(float), stream);

    prep_kernel<<<147, 256, 0, stream>>>(Wc, Wt);
    topk_kernel<<<8, 512, 0, stream>>>(boxes, scores, labels, out, selbox, flags);
    ffconv_kernel<<<dim3(64, 8), 256, 0, stream>>>(x, Wt, bc, pooled);
    cropconv_kernel<<<160, 256, 0, stream>>>(x, Wt, bc, selbox, flags, pooled);
    fc_kernel<<<dim3(16, 7), 256, 0, stream>>>(pooled, Wf, bf, flags, out);
}

// Round 3
// 239.100 us; speedup vs baseline: 127.7518x; 18.8174x over previous
//
#include <hip/hip_runtime.h>
#include <hip/hip_bf16.h>

// Output layout (floats): Objects[8*20*4] @0 | Object_features[8*20*4096] @640
//                        | valid[8*20] @656000 | fullframe_features[8*4096] @656160
#define OBJ_OFF   0
#define FEAT_OFF  640
#define VALID_OFF 656000
#define FF_OFF    656160

// ws layout: pooled[168*256] f32 | selbox[160*4] f32 | flags[160] f32 | Wb[256*168] bf16
#define POOLED_N  (168 * 256)
#define SELBOX_N  (160 * 4)
#define FLAGS_N   (160)

typedef __attribute__((ext_vector_type(8))) short short8v;
typedef __attribute__((ext_vector_type(4))) float f32x4;

__device__ __forceinline__ unsigned int rne_bf16(float f) {
    unsigned int u = __float_as_uint(f);
    return (u + 0x7FFFu + ((u >> 16) & 1u)) >> 16;
}
__device__ __forceinline__ float bf16f(unsigned int h) {
    return __uint_as_float(h << 16);
}

// ---------------------------------------------------------------------------
// Kernel 0: weights -> bf16 im2col layout Wb[oc][k0..167], zero pad k>=147
// ---------------------------------------------------------------------------
__global__ __launch_bounds__(256) void prep_kernel(
    const float* __restrict__ Wc, unsigned short* __restrict__ Wb)
{
    int i = blockIdx.x * 256 + threadIdx.x;       // 168*256 = 43008 exactly
    int oc = i / 168, k = i % 168;
    float v = (k < 147) ? Wc[oc * 147 + k] : 0.f;
    Wb[i] = (unsigned short)rne_bf16(v);
}

// ---------------------------------------------------------------------------
// Kernel 1: per-batch masked top-20 selection (matches lax.top_k ordering)
// ---------------------------------------------------------------------------
__global__ __launch_bounds__(512) void topk_kernel(
    const float* __restrict__ boxes, const float* __restrict__ scores,
    const int* __restrict__ labels, float* __restrict__ d_out,
    float* __restrict__ selbox, float* __restrict__ flags)
{
    __shared__ unsigned long long keys[512];
    __shared__ unsigned long long red[512];
    const int b = blockIdx.x, t = threadIdx.x;

    unsigned long long key = 0ULL;
    if (t < 300) {
        float s = scores[b * 300 + t];
        int   l = labels[b * 300 + t];
        bool cls = (l == 2) || (l == 3) || (l == 4) || (l == 6) || (l == 8);
        if (cls && s > 0.8f) {
            key = ((unsigned long long)__float_as_uint(s) << 32) |
                  (unsigned long long)(unsigned int)(~(unsigned int)t);
        }
    }
    keys[t] = key;
    __syncthreads();

    for (int k = 0; k < 20; ++k) {
        red[t] = keys[t];
        __syncthreads();
        for (int s = 256; s > 0; s >>= 1) {
            if (t < s) red[t] = (red[t] > red[t + s]) ? red[t] : red[t + s];
            __syncthreads();
        }
        unsigned long long m = red[0];
        const int slot = b * 20 + k;
        if (m == 0ULL) {
            if (t == 0) {
                d_out[OBJ_OFF + slot * 4 + 0] = 0.f;
                d_out[OBJ_OFF + slot * 4 + 1] = 0.f;
                d_out[OBJ_OFF + slot * 4 + 2] = 0.f;
                d_out[OBJ_OFF + slot * 4 + 3] = 0.f;
                d_out[VALID_OFF + slot] = 0.f;
                selbox[slot * 4 + 0] = 0.f; selbox[slot * 4 + 1] = 0.f;
                selbox[slot * 4 + 2] = 0.f; selbox[slot * 4 + 3] = 0.f;
                flags[slot] = 0.f;
            }
        } else if (keys[t] == m) {  // unique winner (index embedded in key)
            const float bx0 = boxes[(b * 300 + t) * 4 + 0];
            const float by0 = boxes[(b * 300 + t) * 4 + 1];
            const float bx1 = boxes[(b * 300 + t) * 4 + 2];
            const float by1 = boxes[(b * 300 + t) * 4 + 3];
            d_out[OBJ_OFF + slot * 4 + 0] = bx0;
            d_out[OBJ_OFF + slot * 4 + 1] = by0;
            d_out[OBJ_OFF + slot * 4 + 2] = bx1;
            d_out[OBJ_OFF + slot * 4 + 3] = by1;
            d_out[VALID_OFF + slot] = 1.f;
            selbox[slot * 4 + 0] = bx0; selbox[slot * 4 + 1] = by0;
            selbox[slot * 4 + 2] = bx1; selbox[slot * 4 + 3] = by1;
            bool deg = (bx1 <= bx0) || (by1 <= by0);
            flags[slot] = deg ? 0.f : 1.f;
            keys[t] = 0ULL;
        }
        __syncthreads();
    }
}

// ---------------------------------------------------------------------------
// MFMA GEMM core: [64 pix x K=160] (hi+lo bf16) @ Wb[256 oc x 160] -> relu ->
// pixel-sum -> atomicAdd into pooled[prow][oc]. 4 waves, each 64pix x 64oc.
// A-frag (16x32): lane l holds row (l&15), k-octet (l>>4). B-frag: col (l&15).
// D-frag: col (l&15), row (l>>4)*4+reg  [m89-verified].
// ---------------------------------------------------------------------------
__device__ __forceinline__ void conv_mfma_core(
    const unsigned short (&im2h)[64][168], const unsigned short (&im2l)[64][168],
    const unsigned short* __restrict__ Wb, const float* __restrict__ bc,
    float* __restrict__ pooled, int prow, int tid)
{
    const int w = tid >> 6, l = tid & 63;
    const int lr = l & 15, lq = l >> 4;
    const int n0 = w * 64;

    f32x4 acc[4][4];
#pragma unroll
    for (int mf = 0; mf < 4; ++mf)
#pragma unroll
        for (int nf = 0; nf < 4; ++nf)
            acc[mf][nf] = (f32x4){0.f, 0.f, 0.f, 0.f};

#pragma unroll
    for (int ks = 0; ks < 5; ++ks) {
        const int koff = ks * 32 + lq * 8;
        short8v ah[4], al[4], bf[4];
#pragma unroll
        for (int mf = 0; mf < 4; ++mf) {
            ah[mf] = *(const short8v*)&im2h[mf * 16 + lr][koff];
            al[mf] = *(const short8v*)&im2l[mf * 16 + lr][koff];
        }
#pragma unroll
        for (int nf = 0; nf < 4; ++nf)
            bf[nf] = *(const short8v*)&Wb[(n0 + nf * 16 + lr) * 168 + koff];
#pragma unroll
        for (int mf = 0; mf < 4; ++mf)
#pragma unroll
            for (int nf = 0; nf < 4; ++nf) {
                acc[mf][nf] = __builtin_amdgcn_mfma_f32_16x16x32_bf16(
                    al[mf], bf[nf], acc[mf][nf], 0, 0, 0);
                acc[mf][nf] = __builtin_amdgcn_mfma_f32_16x16x32_bf16(
                    ah[mf], bf[nf], acc[mf][nf], 0, 0, 0);
            }
    }

#pragma unroll
    for (int nf = 0; nf < 4; ++nf) {
        const int oc = n0 + nf * 16 + lr;
        const float bias = bc[oc];
        float s = 0.f;
#pragma unroll
        for (int mf = 0; mf < 4; ++mf)
#pragma unroll
            for (int r = 0; r < 4; ++r) {
                float pv = acc[mf][nf][r] + bias;
                s += pv > 0.f ? pv : 0.f;
            }
        s += __shfl_down(s, 32);
        s += __shfl_down(s, 16);
        if (l < 16) atomicAdd(&pooled[prow * 256 + oc], s);
    }
}

// pack 8 fp32 -> hi/lo bf16 octet and store to LDS
__device__ __forceinline__ void pack_store(
    unsigned short (&im2h)[64][168], unsigned short (&im2l)[64][168],
    int p, int oct, const float* v)
{
    unsigned int hw[4], lw[4];
#pragma unroll
    for (int jj = 0; jj < 4; ++jj) {
        unsigned int h0 = rne_bf16(v[2 * jj]), h1 = rne_bf16(v[2 * jj + 1]);
        float l0 = v[2 * jj] - bf16f(h0);
        float l1 = v[2 * jj + 1] - bf16f(h1);
        hw[jj] = h0 | (h1 << 16);
        lw[jj] = rne_bf16(l0) | (rne_bf16(l1) << 16);
    }
    *(uint4*)&im2h[p][oct * 8] = make_uint4(hw[0], hw[1], hw[2], hw[3]);
    *(uint4*)&im2l[p][oct * 8] = make_uint4(lw[0], lw[1], lw[2], lw[3]);
}

// ---------------------------------------------------------------------------
// Kernel 2: fullframe conv via im2col + MFMA. Block = 4x16 output pixels.
// grid: (256 tiles, 8 batch) x 256 threads
// ---------------------------------------------------------------------------
__global__ __launch_bounds__(256) void ffconv_mfma(
    const float* __restrict__ x, const unsigned short* __restrict__ Wb,
    const float* __restrict__ bc, float* __restrict__ pooled)
{
    __shared__ __align__(16) unsigned short im2h[64][168];
    __shared__ __align__(16) unsigned short im2l[64][168];

    const int b = blockIdx.y;
    const int tile_x = blockIdx.x & 7, tile_y = blockIdx.x >> 3;
    const int tid = threadIdx.x;
    const int p = tid & 63, och = tid >> 6;   // wave-uniform octet group
    const int iy_base = tile_y * 16 + (p >> 4) * 4 - 1;
    const int ix_base = tile_x * 64 + (p & 15) * 4 - 1;

    const float mean[3] = {0.485f, 0.456f, 0.406f};
    const float istd[3] = {1.0f / 0.229f, 1.0f / 0.224f, 1.0f / 0.225f};
    const float* __restrict__ img = x + (size_t)b * 3 * 512 * 512;

#pragma unroll
    for (int oct = 0; oct < 21; ++oct) {
        if ((oct & 3) != och) continue;
        float v[8];
#pragma unroll
        for (int j = 0; j < 8; ++j) {
            const int k = oct * 8 + j;
            float val = 0.f;
            if (k < 147) {
                const int c = k / 49, r = (k % 49) / 7, q = k % 7;
                const int gy = iy_base + r, gx = ix_base + q;
                if (gy >= 0 && gy < 512 && gx >= 0 && gx < 512)
                    val = (img[(c * 512 + gy) * 512 + gx] - mean[c]) * istd[c];
            }
            v[j] = val;
        }
        pack_store(im2h, im2l, p, oct, v);
    }
    __syncthreads();
    conv_mfma_core(im2h, im2l, Wb, bc, pooled, b, tid);
}

// ---------------------------------------------------------------------------
// Kernel 3: RoIAlign crop conv via im2col + MFMA. 4 blocks per crop.
// grid: 640 blocks x 256 threads. Skips invalid/degenerate slots.
// ---------------------------------------------------------------------------
__global__ __launch_bounds__(256) void cropconv_mfma(
    const float* __restrict__ x, const unsigned short* __restrict__ Wb,
    const float* __restrict__ bc, const float* __restrict__ selbox,
    const float* __restrict__ flags, float* __restrict__ pooled)
{
    const int bk = blockIdx.x >> 2, quarter = blockIdx.x & 3;
    if (flags[bk] == 0.f) return;     // features get zeroed anyway
    const int b = bk / 20;
    const int tid = threadIdx.x;

    __shared__ __align__(16) unsigned short im2h[64][168];
    __shared__ __align__(16) unsigned short im2l[64][168];

    const int p = tid & 63, och = tid >> 6;
    const int cy_base = quarter * 16 + (p >> 4) * 4 - 1;   // crop-space row
    const int cx_base = (p & 15) * 4 - 1;

    const float bx0 = selbox[bk * 4 + 0], by0 = selbox[bk * 4 + 1];
    const float bx1 = selbox[bk * 4 + 2], by1 = selbox[bk * 4 + 3];
    const float sy = (by1 - by0) * (1.f / 64.f);
    const float sx = (bx1 - bx0) * (1.f / 64.f);

    const float mean[3] = {0.485f, 0.456f, 0.406f};
    const float istd[3] = {1.0f / 0.229f, 1.0f / 0.224f, 1.0f / 0.225f};
    const float* __restrict__ img = x + (size_t)b * 3 * 512 * 512;

#pragma unroll
    for (int oct = 0; oct < 21; ++oct) {
        if ((oct & 3) != och) continue;
        float v[8];
#pragma unroll
        for (int j = 0; j < 8; ++j) {
            const int k = oct * 8 + j;
            float val = 0.f;
            if (k < 147) {
                const int c = k / 49, r = (k % 49) / 7, q = k % 7;
                const int cy = cy_base + r, cx = cx_base + q;
                if (cy >= 0 && cy < 64 && cx >= 0 && cx < 64) {
                    float ys = by0 + ((float)cy + 0.5f) * sy;
                    float xs = bx0 + ((float)cx + 0.5f) * sx;
                    float yf = floorf(ys), xf = floorf(xs);
                    float wy = ys - yf, wx = xs - xf;
                    int iy0 = min(max((int)yf, 0), 511), iy1 = min(iy0 + 1, 511);
                    int ix0 = min(max((int)xf, 0), 511), ix1 = min(ix0 + 1, 511);
                    const float* ch = img + c * 512 * 512;
                    float Ia = ch[iy0 * 512 + ix0], Ib = ch[iy0 * 512 + ix1];
                    float Ic = ch[iy1 * 512 + ix0], Id = ch[iy1 * 512 + ix1];
                    float s = Ia * (1.f - wy) * (1.f - wx) + Ib * (1.f - wy) * wx +
                              Ic * wy * (1.f - wx) + Id * wy * wx;
                    val = (s - mean[c]) * istd[c];
                }
            }
            v[j] = val;
        }
        pack_store(im2h, im2l, p, oct, v);
    }
    __syncthreads();
    conv_mfma_core(im2h, im2l, Wb, bc, pooled, 8 + bk, tid);
}

// ---------------------------------------------------------------------------
// Kernel 4: FC [168,256] @ Wf[256,4096] + bf, scatter to outputs
// grid: (16 col-blocks, 7 row-groups of 24) x 256 threads
// ---------------------------------------------------------------------------
__global__ __launch_bounds__(256) void fc_kernel(
    const float* __restrict__ pooled, const float* __restrict__ Wf,
    const float* __restrict__ bf, const float* __restrict__ flags,
    float* __restrict__ d_out)
{
    __shared__ float p[24][256];
    const int cb = blockIdx.x, rg = blockIdx.y;
    const int tid = threadIdx.x;

    for (int i = tid; i < 24 * 256; i += 256) {
        int r = i >> 8, k = i & 255;
        int R = rg * 24 + r;
        float s = (R < 8) ? (1.f / 16384.f) : (1.f / 256.f);
        p[r][k] = pooled[R * 256 + k] * s;
    }
    __syncthreads();

    float acc[24];
#pragma unroll
    for (int r = 0; r < 24; ++r) acc[r] = 0.f;

    const int col = cb * 256 + tid;
    for (int k = 0; k < 256; k += 4) {
        float w0 = Wf[(k + 0) * 4096 + col];
        float w1 = Wf[(k + 1) * 4096 + col];
        float w2 = Wf[(k + 2) * 4096 + col];
        float w3 = Wf[(k + 3) * 4096 + col];
#pragma unroll
        for (int r = 0; r < 24; ++r) {
            float4 pv = *(const float4*)&p[r][k];
            acc[r] += pv.x * w0 + pv.y * w1 + pv.z * w2 + pv.w * w3;
        }
    }

    const float bias = bf[col];
#pragma unroll
    for (int r = 0; r < 24; ++r) {
        int R = rg * 24 + r;
        float v = acc[r] + bias;
        if (R < 8) {
            d_out[FF_OFF + R * 4096 + col] = v;
        } else {
            int rr = R - 8;
            if (flags[rr] == 0.f) v = 0.f;
            d_out[FEAT_OFF + rr * 4096 + col] = v;
        }
    }
}

// ---------------------------------------------------------------------------
extern "C" void kernel_launch(void* const* d_in, const int* in_sizes, int n_in,
                              void* d_out, int out_size, void* d_ws, size_t ws_size,
                              hipStream_t stream)
{
    const float* x      = (const float*)d_in[0];
    const float* boxes  = (const float*)d_in[1];
    const float* scores = (const float*)d_in[2];
    const int*   labels = (const int*)d_in[3];
    const float* Wc     = (const float*)d_in[4];
    const float* bc     = (const float*)d_in[5];
    const float* Wf     = (const float*)d_in[6];
    const float* bf     = (const float*)d_in[7];
    float* out = (float*)d_out;

    float* pooled = (float*)d_ws;                       // [168][256] f32 sums
    float* selbox = pooled + POOLED_N;                  // [160][4]
    float* flags  = selbox + SELBOX_N;                  // [160]
    unsigned short* Wb = (unsigned short*)(flags + FLAGS_N);  // [256][168] bf16

    hipMemsetAsync(d_ws, 0, POOLED_N * sizeof(float), stream);

    prep_kernel<<<168, 256, 0, stream>>>(Wc, Wb);
    topk_kernel<<<8, 512, 0, stream>>>(boxes, scores, labels, out, selbox, flags);
    ffconv_mfma<<<dim3(256, 8), 256, 0, stream>>>(x, Wb, bc, pooled);
    cropconv_mfma<<<640, 256, 0, stream>>>(x, Wb, bc, selbox, flags, pooled);
    fc_kernel<<<dim3(16, 7), 256, 0, stream>>>(pooled, Wf, bf, flags, out);
}

// Round 7
// 190.354 us; speedup vs baseline: 160.4670x; 1.2561x over previous
//
#include <hip/hip_runtime.h>
#include <hip/hip_bf16.h>

// Output layout (floats): Objects[8*20*4] @0 | Object_features[8*20*4096] @640
//                        | valid[8*20] @656000 | fullframe_features[8*4096] @656160
#define OBJ_OFF   0
#define FEAT_OFF  640
#define VALID_OFF 656000
#define FF_OFF    656160

// ws layout: pooled[168*256] f32 | selbox[160*4] f32 | flags[160] f32 | Wb[256*192] bf16
#define POOLED_N  (168 * 256)
#define SELBOX_N  (160 * 4)
#define FLAGS_N   (160)
#define K3        192   // padded K: c*64 + r*8 + q  (r,q in 0..7; r==7 or q==7 -> zero weight)

typedef __attribute__((ext_vector_type(8))) short short8v;
typedef __attribute__((ext_vector_type(4))) short short4v;
typedef __attribute__((ext_vector_type(4))) float f32x4;

__device__ __forceinline__ unsigned int rne_bf16(float f) {
    unsigned int u = __float_as_uint(f);
    return (u + 0x7FFFu + ((u >> 16) & 1u)) >> 16;
}

// ---------------------------------------------------------------------------
// Kernel 0: weights -> bf16 padded layout Wb[oc][k'], k' = c*64 + r*8 + q
// ---------------------------------------------------------------------------
__global__ __launch_bounds__(256) void prep_kernel(
    const float* __restrict__ Wc, unsigned short* __restrict__ Wb)
{
    int i = blockIdx.x * 256 + threadIdx.x;     // 256*192 = 49152 exactly
    int oc = i / K3, k = i % K3;
    int c = k >> 6, r = (k >> 3) & 7, q = k & 7;
    float v = (r < 7 && q < 7) ? Wc[oc * 147 + c * 49 + r * 7 + q] : 0.f;
    Wb[i] = (unsigned short)rne_bf16(v);
}

// ---------------------------------------------------------------------------
// Kernel 1: per-batch masked top-20 selection (LDS reduction — proven correct;
// the wave-resident shuffle variant from round 4 corrupted Objects).
// ---------------------------------------------------------------------------
__global__ __launch_bounds__(512) void topk_kernel(
    const float* __restrict__ boxes, const float* __restrict__ scores,
    const int* __restrict__ labels, float* __restrict__ d_out,
    float* __restrict__ selbox, float* __restrict__ flags)
{
    __shared__ unsigned long long keys[512];
    __shared__ unsigned long long red[512];
    const int b = blockIdx.x, t = threadIdx.x;

    unsigned long long key = 0ULL;
    if (t < 300) {
        float s = scores[b * 300 + t];
        int   l = labels[b * 300 + t];
        bool cls = (l == 2) || (l == 3) || (l == 4) || (l == 6) || (l == 8);
        if (cls && s > 0.8f) {
            key = ((unsigned long long)__float_as_uint(s) << 32) |
                  (unsigned long long)(unsigned int)(~(unsigned int)t);
        }
    }
    keys[t] = key;
    __syncthreads();

    for (int k = 0; k < 20; ++k) {
        red[t] = keys[t];
        __syncthreads();
        for (int s = 256; s > 0; s >>= 1) {
            if (t < s) red[t] = (red[t] > red[t + s]) ? red[t] : red[t + s];
            __syncthreads();
        }
        unsigned long long m = red[0];
        const int slot = b * 20 + k;
        if (m == 0ULL) {
            if (t == 0) {
                d_out[OBJ_OFF + slot * 4 + 0] = 0.f;
                d_out[OBJ_OFF + slot * 4 + 1] = 0.f;
                d_out[OBJ_OFF + slot * 4 + 2] = 0.f;
                d_out[OBJ_OFF + slot * 4 + 3] = 0.f;
                d_out[VALID_OFF + slot] = 0.f;
                selbox[slot * 4 + 0] = 0.f; selbox[slot * 4 + 1] = 0.f;
                selbox[slot * 4 + 2] = 0.f; selbox[slot * 4 + 3] = 0.f;
                flags[slot] = 0.f;
            }
        } else if (keys[t] == m) {  // unique winner (index embedded in key)
            const float bx0 = boxes[(b * 300 + t) * 4 + 0];
            const float by0 = boxes[(b * 300 + t) * 4 + 1];
            const float bx1 = boxes[(b * 300 + t) * 4 + 2];
            const float by1 = boxes[(b * 300 + t) * 4 + 3];
            d_out[OBJ_OFF + slot * 4 + 0] = bx0;
            d_out[OBJ_OFF + slot * 4 + 1] = by0;
            d_out[OBJ_OFF + slot * 4 + 2] = bx1;
            d_out[OBJ_OFF + slot * 4 + 3] = by1;
            d_out[VALID_OFF + slot] = 1.f;
            selbox[slot * 4 + 0] = bx0; selbox[slot * 4 + 1] = by0;
            selbox[slot * 4 + 2] = bx1; selbox[slot * 4 + 3] = by1;
            bool deg = (bx1 <= bx0) || (by1 <= by0);
            flags[slot] = deg ? 0.f : 1.f;
            keys[t] = 0ULL;
        }
        __syncthreads();
    }
}

// ---------------------------------------------------------------------------
// MFMA conv core, direct from raw bf16 tile[3][20][68] (origin at -1,-1).
// Block: 64 output pix = 4 out-rows x 16 out-cols; 4 waves x 64 oc each.
// A-octet (lane l, frag mf, k-step ks): kq=ks*4+(l>>4); c=kq>>3, rr=kq&7;
//   8 contiguous bf16 at tile[c][mf*4+rr][(l&15)*4 .. +7]  (weight-pad kills
//   the r==7 / q==7 lanes). D: col=l&15 (oc), row-in-frag = (l>>4)*4+reg.
// ---------------------------------------------------------------------------
__device__ __forceinline__ void conv_core(
    const unsigned short (&tile)[3][20][68],
    const unsigned short* __restrict__ Wb, const float* __restrict__ bc,
    float* __restrict__ pooled, int prow, int tid)
{
    const int w = tid >> 6, l = tid & 63;
    const int lr = l & 15, lq = l >> 4;
    const int n0 = w * 64;

    f32x4 acc[4][4];
#pragma unroll
    for (int mf = 0; mf < 4; ++mf)
#pragma unroll
        for (int nf = 0; nf < 4; ++nf)
            acc[mf][nf] = (f32x4){0.f, 0.f, 0.f, 0.f};

#pragma unroll
    for (int ks = 0; ks < 6; ++ks) {
        const int kq = ks * 4 + lq;          // octet index 0..23
        const int c = kq >> 3, rr = kq & 7;
        const int koff = ks * 32 + lq * 8;

        short8v a[4], bfr[4];
#pragma unroll
        for (int mf = 0; mf < 4; ++mf) {
            const unsigned short* ap = &tile[c][mf * 4 + rr][lr * 4];
            short4v a0 = *(const short4v*)ap;
            short4v a1 = *(const short4v*)(ap + 4);
            a[mf] = __builtin_shufflevector(a0, a1, 0, 1, 2, 3, 4, 5, 6, 7);
        }
#pragma unroll
        for (int nf = 0; nf < 4; ++nf)
            bfr[nf] = *(const short8v*)&Wb[(size_t)(n0 + nf * 16 + lr) * K3 + koff];
#pragma unroll
        for (int mf = 0; mf < 4; ++mf)
#pragma unroll
            for (int nf = 0; nf < 4; ++nf)
                acc[mf][nf] = __builtin_amdgcn_mfma_f32_16x16x32_bf16(
                    a[mf], bfr[nf], acc[mf][nf], 0, 0, 0);
    }

#pragma unroll
    for (int nf = 0; nf < 4; ++nf) {
        const int oc = n0 + nf * 16 + lr;
        const float bias = bc[oc];
        float s = 0.f;
#pragma unroll
        for (int mf = 0; mf < 4; ++mf)
#pragma unroll
            for (int r = 0; r < 4; ++r) {
                float pv = acc[mf][nf][r] + bias;
                s += pv > 0.f ? pv : 0.f;
            }
        s += __shfl_down(s, 32);
        s += __shfl_down(s, 16);
        if (l < 16) atomicAdd(&pooled[prow * 256 + oc], s);
    }
}

// ---------------------------------------------------------------------------
// Kernel 2: fullframe conv. grid (256 tiles = 32 row-groups x 8 col-groups, 8 b)
// ---------------------------------------------------------------------------
__global__ __launch_bounds__(256) void ffconv_mfma(
    const float* __restrict__ x, const unsigned short* __restrict__ Wb,
    const float* __restrict__ bc, float* __restrict__ pooled)
{
    __shared__ __align__(16) unsigned short tile[3][20][68];
    const int b = blockIdx.y;
    const int tile_y = blockIdx.x >> 3;   // out-rows tile_y*4 .. +3
    const int tile_x = blockIdx.x & 7;    // out-cols tile_x*16 .. +15
    const int tid = threadIdx.x;
    const int iy0 = tile_y * 16 - 1, ix0 = tile_x * 64 - 1;

    const float mean[3] = {0.485f, 0.456f, 0.406f};
    const float istd[3] = {1.0f / 0.229f, 1.0f / 0.224f, 1.0f / 0.225f};

    for (int i = tid; i < 3 * 20 * 68; i += 256) {
        int c = i / 1360, rem = i % 1360;
        int ir = rem / 68, icol = rem % 68;
        int gy = iy0 + ir, gx = ix0 + icol;
        float v = 0.f;
        if (gy >= 0 && gy < 512 && gx >= 0 && gx < 512)
            v = (x[((size_t)(b * 3 + c) * 512 + gy) * 512 + gx] - mean[c]) * istd[c];
        tile[c][ir][icol] = (unsigned short)rne_bf16(v);
    }
    __syncthreads();
    conv_core(tile, Wb, bc, pooled, b, tid);
}

// ---------------------------------------------------------------------------
// Kernel 3: crop conv. grid 640 = 160 (b,k) x 4 quarters (4 out-rows each).
// ---------------------------------------------------------------------------
__global__ __launch_bounds__(256) void cropconv_mfma(
    const float* __restrict__ x, const unsigned short* __restrict__ Wb,
    const float* __restrict__ bc, const float* __restrict__ selbox,
    const float* __restrict__ flags, float* __restrict__ pooled)
{
    const int bk = blockIdx.x >> 2, quarter = blockIdx.x & 3;
    if (flags[bk] == 0.f) return;          // features get zeroed anyway
    const int b = bk / 20;
    const int tid = threadIdx.x;

    __shared__ __align__(16) unsigned short tile[3][20][68];

    const float bx0 = selbox[bk * 4 + 0], by0 = selbox[bk * 4 + 1];
    const float bx1 = selbox[bk * 4 + 2], by1 = selbox[bk * 4 + 3];
    const float sy = (by1 - by0) * (1.f / 64.f);
    const float sx = (bx1 - bx0) * (1.f / 64.f);

    const float mean[3] = {0.485f, 0.456f, 0.406f};
    const float istd[3] = {1.0f / 0.229f, 1.0f / 0.224f, 1.0f / 0.225f};
    const float* __restrict__ img = x + (size_t)b * 3 * 512 * 512;

    for (int i = tid; i < 3 * 20 * 68; i += 256) {
        int c = i / 1360, rem = i % 1360;
        int ir = rem / 68, icol = rem % 68;
        int cy = quarter * 16 - 1 + ir;    // crop-space row
        int cx = icol - 1;                 // crop-space col
        float v = 0.f;
        if (cy >= 0 && cy < 64 && cx >= 0 && cx < 64) {
            float ys = by0 + ((float)cy + 0.5f) * sy;
            float xs = bx0 + ((float)cx + 0.5f) * sx;
            float yf = floorf(ys), xf = floorf(xs);
            float wy = ys - yf, wx = xs - xf;
            int iy0 = min(max((int)yf, 0), 511), iy1 = min(iy0 + 1, 511);
            int ix0 = min(max((int)xf, 0), 511), ix1 = min(ix0 + 1, 511);
            const float* ch = img + (size_t)c * 512 * 512;
            float Ia = ch[iy0 * 512 + ix0], Ib = ch[iy0 * 512 + ix1];
            float Ic = ch[iy1 * 512 + ix0], Id = ch[iy1 * 512 + ix1];
            float s = Ia * (1.f - wy) * (1.f - wx) + Ib * (1.f - wy) * wx +
                      Ic * wy * (1.f - wx) + Id * wy * wx;
            v = (s - mean[c]) * istd[c];
        }
        tile[c][ir][icol] = (unsigned short)rne_bf16(v);
    }
    __syncthreads();
    conv_core(tile, Wb, bc, pooled, 8 + bk, tid);
}

// ---------------------------------------------------------------------------
// Kernel 4: FC [168,256] @ Wf[256,4096] + bf, K-split x4, atomicAdd epilogue.
// grid (16 col-blocks x 256, 7 row-groups x 24, 4 k-splits x 64)
// ---------------------------------------------------------------------------
__global__ __launch_bounds__(256) void fc_kernel(
    const float* __restrict__ pooled, const float* __restrict__ Wf,
    const float* __restrict__ bf, const float* __restrict__ flags,
    float* __restrict__ d_out)
{
    __shared__ __align__(16) float p[24][64];
    const int cb = blockIdx.x, rg = blockIdx.y, kz = blockIdx.z;
    const int tid = threadIdx.x;

    for (int i = tid; i < 24 * 64; i += 256) {
        int r = i >> 6, k = i & 63;
        int R = rg * 24 + r;
        float s = (R < 8) ? (1.f / 16384.f) : (1.f / 256.f);
        p[r][k] = pooled[R * 256 + kz * 64 + k] * s;
    }
    __syncthreads();

    float acc[24];
#pragma unroll
    for (int r = 0; r < 24; ++r) acc[r] = 0.f;

    const int col = cb * 256 + tid;
    const float* wp = Wf + (size_t)(kz * 64) * 4096 + col;
    for (int k = 0; k < 64; k += 4) {
        float w0 = wp[(size_t)(k + 0) * 4096];
        float w1 = wp[(size_t)(k + 1) * 4096];
        float w2 = wp[(size_t)(k + 2) * 4096];
        float w3 = wp[(size_t)(k + 3) * 4096];
#pragma unroll
        for (int r = 0; r < 24; ++r) {
            float4 pv = *(const float4*)&p[r][k];
            acc[r] += pv.x * w0 + pv.y * w1 + pv.z * w2 + pv.w * w3;
        }
    }

    const float bias_on = (kz == 0) ? 1.f : 0.f;
#pragma unroll
    for (int r = 0; r < 24; ++r) {
        int R = rg * 24 + r;
        float v = acc[r] + bias_on * bf[col];
        if (R < 8) {
            atomicAdd(&d_out[FF_OFF + R * 4096 + col], v);
        } else {
            int rr = R - 8;
            if (flags[rr] != 0.f)
                atomicAdd(&d_out[FEAT_OFF + rr * 4096 + col], v);
        }
    }
}

// ---------------------------------------------------------------------------
extern "C" void kernel_launch(void* const* d_in, const int* in_sizes, int n_in,
                              void* d_out, int out_size, void* d_ws, size_t ws_size,
                              hipStream_t stream)
{
    const float* x      = (const float*)d_in[0];
    const float* boxes  = (const float*)d_in[1];
    const float* scores = (const float*)d_in[2];
    const int*   labels = (const int*)d_in[3];
    const float* Wc     = (const float*)d_in[4];
    const float* bc     = (const float*)d_in[5];
    const float* Wf     = (const float*)d_in[6];
    const float* bf     = (const float*)d_in[7];
    float* out = (float*)d_out;

    float* pooled = (float*)d_ws;                       // [168][256] f32 sums
    float* selbox = pooled + POOLED_N;                  // [160][4]
    float* flags  = selbox + SELBOX_N;                  // [160]
    unsigned short* Wb = (unsigned short*)(flags + FLAGS_N);  // [256][192] bf16

    hipMemsetAsync(d_ws, 0, POOLED_N * sizeof(float), stream);
    hipMemsetAsync(d_out, 0, (size_t)out_size * sizeof(float), stream);

    prep_kernel<<<K3, 256, 0, stream>>>(Wc, Wb);
    topk_kernel<<<8, 512, 0, stream>>>(boxes, scores, labels, out, selbox, flags);
    ffconv_mfma<<<dim3(256, 8), 256, 0, stream>>>(x, Wb, bc, pooled);
    cropconv_mfma<<<640, 256, 0, stream>>>(x, Wb, bc, selbox, flags, pooled);
    fc_kernel<<<dim3(16, 7, 4), 256, 0, stream>>>(pooled, Wf, bf, flags, out);
}